// Round 1
// baseline (319.684 us; speedup 1.0000x reference)
//
#include <hip/hip_runtime.h>
#include <hip/hip_bf16.h>

// Graph mean aggregation: out[n, 32] = (sum over edges e with dst[e]==n of h[src[e]]) / max(deg[n],1)
// Inputs: d_in[0] = h float32 [N_NODES, 32]
//         d_in[1] = src int32 [N_EDGES]   (harness delivers integer inputs as int32)
//         d_in[2] = dst int32 [N_EDGES]
// Output: d_out float32 [N_NODES, 32]
// Workspace: deg float32 [N_NODES]

#define D_FEAT 32

__global__ void zero_init_kernel(float* __restrict__ out, int out_n,
                                 float* __restrict__ deg, int n_nodes) {
    int total = out_n + n_nodes;
    for (int i = blockIdx.x * blockDim.x + threadIdx.x; i < total;
         i += gridDim.x * blockDim.x) {
        if (i < out_n) out[i] = 0.0f;
        else deg[i - out_n] = 0.0f;
    }
}

__global__ void scatter_kernel(const float* __restrict__ h,
                               const int* __restrict__ src,
                               const int* __restrict__ dst,
                               float* __restrict__ out,
                               float* __restrict__ deg,
                               int n_edges) {
    // one (edge, feat) pair per thread: 32 threads handle one edge
    long long tid = (long long)blockIdx.x * blockDim.x + threadIdx.x;
    long long total = (long long)n_edges * D_FEAT;
    if (tid >= total) return;
    int e = (int)(tid >> 5);      // edge index
    int d = (int)(tid & 31);      // feature index
    int s = src[e];
    int t = dst[e];
    float v = h[(long long)s * D_FEAT + d];
    atomicAdd(&out[(long long)t * D_FEAT + d], v);
    if (d == 0) atomicAdd(&deg[t], 1.0f);
}

__global__ void finalize_kernel(float* __restrict__ out,
                                const float* __restrict__ deg,
                                int n_nodes) {
    int total = n_nodes * D_FEAT;
    for (int i = blockIdx.x * blockDim.x + threadIdx.x; i < total;
         i += gridDim.x * blockDim.x) {
        float dg = deg[i >> 5];
        out[i] = out[i] / fmaxf(dg, 1.0f);
    }
}

extern "C" void kernel_launch(void* const* d_in, const int* in_sizes, int n_in,
                              void* d_out, int out_size, void* d_ws, size_t ws_size,
                              hipStream_t stream) {
    const float* h  = (const float*)d_in[0];
    const int* src  = (const int*)d_in[1];
    const int* dst  = (const int*)d_in[2];
    float* out      = (float*)d_out;

    int n_nodes = in_sizes[0] / D_FEAT;
    int n_edges = in_sizes[1];

    float* deg = (float*)d_ws;   // n_nodes floats of scratch

    // 1) zero output + degree (harness poisons them with 0xAA)
    {
        int total = n_nodes * D_FEAT + n_nodes;
        int block = 256;
        int grid  = min((total + block - 1) / block, 2048);
        zero_init_kernel<<<grid, block, 0, stream>>>(out, n_nodes * D_FEAT, deg, n_nodes);
    }

    // 2) scatter-add messages + degree
    {
        long long total = (long long)n_edges * D_FEAT;
        int block = 256;
        long long grid = (total + block - 1) / block;
        scatter_kernel<<<(int)grid, block, 0, stream>>>(h, src, dst, out, deg, n_edges);
    }

    // 3) normalize by degree
    {
        int total = n_nodes * D_FEAT;
        int block = 256;
        int grid  = min((total + block - 1) / block, 2048);
        finalize_kernel<<<grid, block, 0, stream>>>(out, deg, n_nodes);
    }
}